// Round 2
// baseline (382.461 us; speedup 1.0000x reference)
//
#include <hip/hip_runtime.h>
#include <hip/hip_bf16.h>

// out[b,i,k] = sum_j tanh(bn2( relu(bn1( [x_i,x_j,adj_ij] @ W1 )) @ W2 ))[k]
// Phase-1 (per j-tile): H1 = relu(P1t[i,h] + P2T[h,j] + adj@W1a) via MFMA (K=16 pad 32)
// Phase-2: H1 @ W2s via MFMA; tanh via exp2/rcp with 2*log2e prefolded into W2s,t2.

typedef short short8 __attribute__((ext_vector_type(8)));
typedef float f32x4 __attribute__((ext_vector_type(4)));
typedef unsigned int u32x2 __attribute__((ext_vector_type(2)));

#define EPSV 1e-5f
#define TWO_LOG2E 2.885390081777927f

// ws layout (float offsets):
#define OFF_P1T  0         // [1024][256] f32
#define OFF_P2T  262144    // [2][256][512] f32 (transposed: [b][h][j])
#define OFF_S1   524288
#define OFF_T1   524544
#define OFF_T2   524800    // t2 * 2log2e
#define OFF_W1AT 525056    // bf16 [256 h][32 k] (k>=16 zero) = 4096 floats
#define OFF_W2ST 529152    // bf16 [256 kout][256 h] * s2 * 2log2e

__device__ __forceinline__ short f2bf(float f) {
    unsigned u = __builtin_bit_cast(unsigned, f);
    u += 0x7fffu + ((u >> 16) & 1u);
    return (short)(u >> 16);
}

__device__ __forceinline__ unsigned pk2bf(float lo, float hi) {
    unsigned u;
    asm("v_cvt_pk_bf16_f32 %0, %1, %2" : "=v"(u) : "v"(lo), "v"(hi));
    return u;
}

__device__ __forceinline__ float fexp2(float x) {
#if __has_builtin(__builtin_amdgcn_exp2f)
    return __builtin_amdgcn_exp2f(x);
#else
    return exp2f(x);
#endif
}

__global__ void prep_scalars(const float* __restrict__ W1,
                             const float* __restrict__ g1, const float* __restrict__ b1,
                             const float* __restrict__ m1, const float* __restrict__ v1,
                             const float* __restrict__ g2, const float* __restrict__ b2,
                             const float* __restrict__ m2, const float* __restrict__ v2,
                             float* __restrict__ wsf) {
    int t = threadIdx.x;  // h (0..255)
    float s1 = g1[t] * __frsqrt_rn(v1[t] + EPSV);
    float t1 = b1[t] - m1[t] * s1;
    float s2 = g2[t] * __frsqrt_rn(v2[t] + EPSV);
    float t2 = b2[t] - m2[t] * s2;
    wsf[OFF_S1 + t] = s1;
    wsf[OFF_T1 + t] = t1;
    wsf[OFF_T2 + t] = t2 * TWO_LOG2E;
    short* W1aT = (short*)(wsf + OFF_W1AT);   // [h][32]
#pragma unroll
    for (int d = 0; d < 16; ++d)
        W1aT[t * 32 + d] = f2bf(W1[(256 + d) * 256 + t] * s1);
#pragma unroll
    for (int d = 16; d < 32; ++d)
        W1aT[t * 32 + d] = 0;
}

__global__ void prep_w2(const float* __restrict__ W2,
                        const float* __restrict__ g2, const float* __restrict__ v2,
                        float* __restrict__ wsf) {
    int k = blockIdx.x, h = threadIdx.x;
    float s2 = g2[k] * __frsqrt_rn(v2[k] + EPSV) * TWO_LOG2E;
    short* W2sT = (short*)(wsf + OFF_W2ST);
    W2sT[k * 256 + h] = f2bf(W2[h * 256 + k] * s2);
}

__global__ void prep_p(const float* __restrict__ inp, const float* __restrict__ W1,
                       float* __restrict__ wsf) {
    int bn = blockIdx.x, h = threadIdx.x;
    const float* x = inp + (size_t)bn * 128;
    float a1 = 0.f, a2 = 0.f;
    for (int c = 0; c < 128; ++c) {
        float xv = x[c];
        a1 = fmaf(xv, W1[c * 256 + h], a1);
        a2 = fmaf(xv, W1[(128 + c) * 256 + h], a2);
    }
    float s1 = wsf[OFF_S1 + h], t1 = wsf[OFF_T1 + h];
    wsf[OFF_P1T + (size_t)bn * 256 + h] = a1 * s1 + t1;
    int b = bn >> 9, j = bn & 511;
    wsf[OFF_P2T + (size_t)b * 131072 + (size_t)h * 512 + j] = a2 * s1;
}

__global__ __launch_bounds__(256, 2) void propmain(
    const float* __restrict__ adj, const float* __restrict__ wsf,
    float* __restrict__ out) {
    __shared__ short h1buf[64 * 256];   // bf16 H1 tile, XOR-swizzled (32 KB)
    __shared__ short adjbf[64 * 40];    // bf16 adj tile, K-padded, row stride 40 (5 KB)

    const int bi = blockIdx.x;
    const int b = bi >> 9;
    const int t = threadIdx.x;
    const int w = t >> 6, l = t & 63, r = l & 15, q = l >> 4;

    const float* P1t = wsf + OFF_P1T;
    const float* P2Tb = wsf + OFF_P2T + (size_t)b * 131072;
    const float* t2p = wsf + OFF_T2;
    const short* W1aT = (const short*)(wsf + OFF_W1AT);
    const short* W2sT = (const short*)(wsf + OFF_W2ST);

    // per-wave column slice: h = w*64 + n*16 + r
    short8 bB1[4];
    short8 bB2[4][8];
    float t2v[4], p1v[4];
#pragma unroll
    for (int n = 0; n < 4; ++n) {
        const int hc = w * 64 + n * 16 + r;
        bB1[n] = *(const short8*)(W1aT + hc * 32 + q * 8);
#pragma unroll
        for (int s = 0; s < 8; ++s)
            bB2[n][s] = *(const short8*)(W2sT + hc * 256 + s * 32 + q * 8);
        t2v[n] = t2p[hc];
        p1v[n] = P1t[(size_t)bi * 256 + hc];
    }

    // zero the K-pad of adjbf once
    if (t < 64) {
#pragma unroll
        for (int d = 16; d < 40; ++d) adjbf[t * 40 + d] = 0;
    }

    float part[4] = {0.f, 0.f, 0.f, 0.f};
    const float* adjbase = adj + (size_t)bi * 512 * 16;

    for (int jt = 0; jt < 8; ++jt) {
        const int jbase = jt * 64;
        // stage adj tile -> bf16 LDS (64 rows x 16 k, stride 40)
        {
            const float4 av = *(const float4*)(adjbase + jbase * 16 + t * 4);
            const int row = t >> 2, dc = (t & 3) * 4;
            u32x2 u;
            u.x = pk2bf(av.x, av.y);
            u.y = pk2bf(av.z, av.w);
            *(u32x2*)(adjbf + row * 40 + dc) = u;
        }
        __syncthreads();

        // phase 1: H1 = relu(P1 + P2 + adj@W1a) via MFMA, write bf16 swizzled LDS
        {
            short8 aA1[4];
#pragma unroll
            for (int rf = 0; rf < 4; ++rf)
                aA1[rf] = *(const short8*)(adjbf + (rf * 16 + r) * 40 + q * 8);
            f32x4 acc1[4][4];
#pragma unroll
            for (int rf = 0; rf < 4; ++rf)
#pragma unroll
                for (int n = 0; n < 4; ++n)
                    acc1[rf][n] = (f32x4){p1v[n], p1v[n], p1v[n], p1v[n]};
#pragma unroll
            for (int rf = 0; rf < 4; ++rf)
#pragma unroll
                for (int n = 0; n < 4; ++n)
                    acc1[rf][n] = __builtin_amdgcn_mfma_f32_16x16x32_bf16(
                        aA1[rf], bB1[n], acc1[rf][n], 0, 0, 0);
#pragma unroll
            for (int rf = 0; rf < 4; ++rf)
#pragma unroll
                for (int n = 0; n < 4; ++n) {
                    const int colb = w * 64 + n * 16 + r;
                    const f32x4 p2 = *(const f32x4*)(P2Tb + (size_t)colb * 512 +
                                                     jbase + rf * 16 + q * 4);
#pragma unroll
                    for (int e = 0; e < 4; ++e) {
                        float y = acc1[rf][n][e] + p2[e];
                        y = fmaxf(y, 0.f);
                        const int row = rf * 16 + q * 4 + e;
                        h1buf[row * 256 + (colb ^ ((row & 7) << 3))] =
                            (short)pk2bf(y, y);
                    }
                }
        }
        __syncthreads();

        // phase 2: H1 @ W2s via MFMA, acc init = t2 (scaled), then exp2/rcp sum
        {
            f32x4 acc[4][4];
#pragma unroll
            for (int rf = 0; rf < 4; ++rf)
#pragma unroll
                for (int n = 0; n < 4; ++n)
                    acc[rf][n] = (f32x4){t2v[n], t2v[n], t2v[n], t2v[n]};
#pragma unroll
            for (int s = 0; s < 8; ++s) {
                short8 aA[4];
#pragma unroll
                for (int rf = 0; rf < 4; ++rf) {
                    const int row = rf * 16 + r;
                    aA[rf] = *(const short8*)(h1buf + row * 256 +
                                              ((s * 32 + q * 8) ^ ((row & 7) << 3)));
                }
#pragma unroll
                for (int rf = 0; rf < 4; ++rf)
#pragma unroll
                    for (int n = 0; n < 4; ++n)
                        acc[rf][n] = __builtin_amdgcn_mfma_f32_16x16x32_bf16(
                            aA[rf], bB2[n][s], acc[rf][n], 0, 0, 0);
            }
#pragma unroll
            for (int n = 0; n < 4; ++n) {
                float ps = 0.f;
#pragma unroll
                for (int rf = 0; rf < 4; ++rf)
#pragma unroll
                    for (int e = 0; e < 4; ++e) {
                        const float ex = fexp2(acc[rf][n][e]);
                        ps += __builtin_amdgcn_rcpf(ex + 1.f);
                    }
                part[n] += ps;
            }
        }
        __syncthreads();
    }

    // tanh sum = 512 - 2 * sum(rcp); reduce over q-groups
#pragma unroll
    for (int n = 0; n < 4; ++n) {
        float v = part[n];
        v += __shfl_xor(v, 16, 64);
        v += __shfl_xor(v, 32, 64);
        if (q == 0) out[(size_t)bi * 256 + w * 64 + n * 16 + r] = 512.f - 2.f * v;
    }
}

extern "C" void kernel_launch(void* const* d_in, const int* in_sizes, int n_in,
                              void* d_out, int out_size, void* d_ws, size_t ws_size,
                              hipStream_t stream) {
    (void)in_sizes; (void)n_in; (void)out_size; (void)ws_size;
    const float* inputs = (const float*)d_in[0];
    const float* adj    = (const float*)d_in[1];
    const float* W1     = (const float*)d_in[2];
    const float* g1     = (const float*)d_in[3];
    const float* b1     = (const float*)d_in[4];
    const float* m1     = (const float*)d_in[5];
    const float* v1     = (const float*)d_in[6];
    const float* W2     = (const float*)d_in[7];
    const float* g2     = (const float*)d_in[8];
    const float* b2     = (const float*)d_in[9];
    const float* m2     = (const float*)d_in[10];
    const float* v2     = (const float*)d_in[11];
    float* out = (float*)d_out;
    float* wsf = (float*)d_ws;

    prep_scalars<<<1, 256, 0, stream>>>(W1, g1, b1, m1, v1, g2, b2, m2, v2, wsf);
    prep_w2<<<256, 256, 0, stream>>>(W2, g2, v2, wsf);
    prep_p<<<1024, 256, 0, stream>>>(inputs, W1, wsf);
    propmain<<<1024, 256, 0, stream>>>(adj, wsf, out);
}

// Round 3
// 181.595 us; speedup vs baseline: 2.1061x; 2.1061x over previous
//
#include <hip/hip_runtime.h>
#include <hip/hip_bf16.h>

// out[b,i,k] = sum_j tanh(bn2( relu(bn1( [x_i,x_j,adj_ij] @ W1 )) @ W2 ))[k]
// Phase-1: acc = P1[h] + adj@W1a (MFMA, K=16 pad 32) -> f32 LDS
// P2-pass: += P2[j,h] (coalesced rows), relu -> bf16 LDS
// Phase-2: H1 @ W2f (register-resident frags) ; tanh via exp2/rcp (2log2e folded)

typedef short short8 __attribute__((ext_vector_type(8)));
typedef float f32x4 __attribute__((ext_vector_type(4)));

#define EPSV 1e-5f
#define TWO_LOG2E 2.885390081777927f

// ws layout (float offsets):
#define OFF_P1T  0         // [1024][256] f32
#define OFF_P2S  262144    // [1024][256] f32 ([b*512+j][h], row-major)
#define OFF_S1   524288
#define OFF_T1   524544
#define OFF_T2   524800    // t2 * 2log2e
#define OFF_W1F  525056    // bf16 frags [16][64][8]  (w*2+n, lane, e)
#define OFF_W2F  529152    // bf16 frags [128][64][8] (w*16+n*8+s, lane, e)

__device__ __forceinline__ short f2bf(float f) {
    unsigned u = __builtin_bit_cast(unsigned, f);
    u += 0x7fffu + ((u >> 16) & 1u);
    return (short)(u >> 16);
}

__device__ __forceinline__ unsigned pk2bf(float lo, float hi) {
    unsigned u;
    asm("v_cvt_pk_bf16_f32 %0, %1, %2" : "=v"(u) : "v"(lo), "v"(hi));
    return u;
}

__device__ __forceinline__ float fexp2(float x) {
#if __has_builtin(__builtin_amdgcn_exp2f)
    return __builtin_amdgcn_exp2f(x);
#else
    return exp2f(x);
#endif
}

__global__ void prep_scalars(const float* __restrict__ g1, const float* __restrict__ b1,
                             const float* __restrict__ m1, const float* __restrict__ v1,
                             const float* __restrict__ g2, const float* __restrict__ b2,
                             const float* __restrict__ m2, const float* __restrict__ v2,
                             float* __restrict__ wsf) {
    int t = threadIdx.x;  // h (0..255)
    float s1 = g1[t] * __frsqrt_rn(v1[t] + EPSV);
    float t1 = b1[t] - m1[t] * s1;
    float s2 = g2[t] * __frsqrt_rn(v2[t] + EPSV);
    float t2 = b2[t] - m2[t] * s2;
    wsf[OFF_S1 + t] = s1;
    wsf[OFF_T1 + t] = t1;
    wsf[OFF_T2 + t] = t2 * TWO_LOG2E;
}

// W1a fragments: frag f = w*2+n, lane l: col = (f>>1)*32 + (f&1)*16 + (l&15),
// k = (l>>4)*8 + e (k<16 real, else 0). val = W1[(256+k)*256+col]*s1[col]
__global__ void prep_w1f(const float* __restrict__ W1, float* __restrict__ wsf) {
    int tid = blockIdx.x * 256 + threadIdx.x;  // 0..1023
    int f = tid >> 6, l = tid & 63;
    int col = (f >> 1) * 32 + (f & 1) * 16 + (l & 15);
    int kb = (l >> 4) * 8;
    float s1 = wsf[OFF_S1 + col];
    short8 v;
#pragma unroll
    for (int e = 0; e < 8; ++e) {
        int k = kb + e;
        v[e] = (k < 16) ? f2bf(W1[(256 + k) * 256 + col] * s1) : (short)0;
    }
    *(short8*)((short*)(wsf + OFF_W1F) + tid * 8) = v;
}

// W2 fragments: frag f = w*16+n*8+s, lane l: col = w*32+n*16+(l&15),
// k = s*32+(l>>4)*8+e. val = W2[k*256+col]*s2[col]*2log2e
__global__ void prep_w2f(const float* __restrict__ W2,
                         const float* __restrict__ g2, const float* __restrict__ v2,
                         float* __restrict__ wsf) {
    int tid = blockIdx.x * 256 + threadIdx.x;  // 0..8191
    int f = tid >> 6, l = tid & 63;
    int w = f >> 4, n = (f >> 3) & 1, s = f & 7;
    int col = w * 32 + n * 16 + (l & 15);
    int kb = s * 32 + (l >> 4) * 8;
    float s2 = g2[col] * __frsqrt_rn(v2[col] + EPSV) * TWO_LOG2E;
    short8 v;
#pragma unroll
    for (int e = 0; e < 8; ++e)
        v[e] = f2bf(W2[(kb + e) * 256 + col] * s2);
    *(short8*)((short*)(wsf + OFF_W2F) + tid * 8) = v;
}

__global__ void prep_p(const float* __restrict__ inp, const float* __restrict__ W1,
                       float* __restrict__ wsf) {
    int bn = blockIdx.x, h = threadIdx.x;
    const float* x = inp + (size_t)bn * 128;
    float a1 = 0.f, a2 = 0.f;
    for (int c = 0; c < 128; ++c) {
        float xv = x[c];
        a1 = fmaf(xv, W1[c * 256 + h], a1);
        a2 = fmaf(xv, W1[(128 + c) * 256 + h], a2);
    }
    float s1 = wsf[OFF_S1 + h], t1 = wsf[OFF_T1 + h];
    wsf[OFF_P1T + (size_t)bn * 256 + h] = a1 * s1 + t1;
    wsf[OFF_P2S + (size_t)bn * 256 + h] = a2 * s1;
}

__global__ __launch_bounds__(512, 2) void propmain(
    const float* __restrict__ adj, const float* __restrict__ wsf,
    float* __restrict__ out) {
    __shared__ float h1f[64 * 256];   // f32 H1 pre-P2, swizzled (64 KB)
    __shared__ short h1b[64 * 256];   // bf16 H1 post-relu, swizzled (32 KB)
    __shared__ short adjbf[64 * 32];  // bf16 adj tile, chunk-XOR layout (4 KB)

    const int bi = blockIdx.x;
    const int b = bi >> 9;
    const int t = threadIdx.x;
    const int w = t >> 6, l = t & 63, r = l & 15, q = l >> 4;

    const float* P1t = wsf + OFF_P1T;
    const float* P2s = wsf + OFF_P2S;
    const float* t2p = wsf + OFF_T2;
    const short* W1f = (const short*)(wsf + OFF_W1F);
    const short* W2f = (const short*)(wsf + OFF_W2F);

    // register-resident fragments (coalesced loads, loop-invariant)
    short8 bB1[2];
    short8 bB2[2][8];
    float t2v[2], p1v[2];
#pragma unroll
    for (int n = 0; n < 2; ++n) {
        bB1[n] = *(const short8*)(W1f + ((w * 2 + n) * 64 + l) * 8);
#pragma unroll
        for (int s = 0; s < 8; ++s)
            bB2[n][s] = *(const short8*)(W2f + ((w * 16 + n * 8 + s) * 64 + l) * 8);
        const int hc = w * 32 + n * 16 + r;
        t2v[n] = t2p[hc];
        p1v[n] = P1t[(size_t)bi * 256 + hc];
    }

    // zero adjbf once (pad chunks stay zero; data chunks overwritten each tile)
    if (t < 256) {
        short8 z = {0, 0, 0, 0, 0, 0, 0, 0};
        *(short8*)(adjbf + t * 8) = z;
    }
    __syncthreads();

    float part[2] = {0.f, 0.f};
    const float* adjbase = adj + (size_t)bi * 512 * 16;

    for (int jt = 0; jt < 8; ++jt) {
        const int jbase = jt * 64;
        // 1. stage adj tile -> bf16 LDS, chunk-XOR swizzle
        {
            const float2 av = *(const float2*)(adjbase + jbase * 16 + t * 2);
            const unsigned pk = pk2bf(av.x, av.y);
            const int row = t >> 3, ks = (t & 7) * 2;
            const int cp = (ks >> 3) ^ (row & 3);
            *(unsigned*)(adjbf + row * 32 + cp * 8 + (ks & 7)) = pk;
        }
        __syncthreads();

        // 2. phase 1: acc = P1 + adj@W1a via MFMA -> f32 swizzled LDS
        {
            short8 aA1[4];
#pragma unroll
            for (int rf = 0; rf < 4; ++rf)
                aA1[rf] = *(const short8*)(adjbf + (rf * 16 + r) * 32 +
                                           (q ^ (r & 3)) * 8);
            f32x4 acc1[4][2];
#pragma unroll
            for (int rf = 0; rf < 4; ++rf)
#pragma unroll
                for (int n = 0; n < 2; ++n)
                    acc1[rf][n] = (f32x4){p1v[n], p1v[n], p1v[n], p1v[n]};
#pragma unroll
            for (int rf = 0; rf < 4; ++rf)
#pragma unroll
                for (int n = 0; n < 2; ++n)
                    acc1[rf][n] = __builtin_amdgcn_mfma_f32_16x16x32_bf16(
                        aA1[rf], bB1[n], acc1[rf][n], 0, 0, 0);
#pragma unroll
            for (int rf = 0; rf < 4; ++rf)
#pragma unroll
                for (int n = 0; n < 2; ++n) {
                    const int colb = w * 32 + n * 16 + r;
#pragma unroll
                    for (int e = 0; e < 4; ++e) {
                        const int row2 = rf * 16 + q * 4 + e;
                        h1f[row2 * 256 + (colb ^ ((row2 & 7) << 3))] = acc1[rf][n][e];
                    }
                }
        }
        __syncthreads();

        // 3. P2 pass: += P2 (coalesced rows), relu, -> bf16 LDS
        {
            const int col = t & 255, jh = t >> 8;
            const float* p2base = P2s + ((size_t)(b * 512 + jbase + jh * 32)) * 256 + col;
#pragma unroll 8
            for (int jj = 0; jj < 32; ++jj) {
                const int j = jh * 32 + jj;
                const int addr = j * 256 + (col ^ ((j & 7) << 3));
                float v = h1f[addr] + p2base[(size_t)jj * 256];
                v = fmaxf(v, 0.f);
                h1b[addr] = f2bf(v);
            }
        }
        __syncthreads();

        // 4. phase 2: H1 @ W2f via MFMA, tanh partial sums
        {
            f32x4 acc[4][2];
#pragma unroll
            for (int rf = 0; rf < 4; ++rf)
#pragma unroll
                for (int n = 0; n < 2; ++n)
                    acc[rf][n] = (f32x4){t2v[n], t2v[n], t2v[n], t2v[n]};
#pragma unroll
            for (int s = 0; s < 8; ++s) {
                short8 aA[4];
#pragma unroll
                for (int rf = 0; rf < 4; ++rf) {
                    const int row = rf * 16 + r;
                    aA[rf] = *(const short8*)(h1b + row * 256 +
                                              ((s * 32 + q * 8) ^ ((row & 7) << 3)));
                }
#pragma unroll
                for (int rf = 0; rf < 4; ++rf)
#pragma unroll
                    for (int n = 0; n < 2; ++n)
                        acc[rf][n] = __builtin_amdgcn_mfma_f32_16x16x32_bf16(
                            aA[rf], bB2[n][s], acc[rf][n], 0, 0, 0);
            }
#pragma unroll
            for (int n = 0; n < 2; ++n) {
                float ps = 0.f;
#pragma unroll
                for (int rf = 0; rf < 4; ++rf)
#pragma unroll
                    for (int e = 0; e < 4; ++e) {
                        const float ex = fexp2(acc[rf][n][e]);
                        ps += __builtin_amdgcn_rcpf(ex + 1.f);
                    }
                part[n] += ps;
            }
        }
        __syncthreads();
    }

    // sum_j tanh = 512 - 2*sum(rcp); reduce over q
#pragma unroll
    for (int n = 0; n < 2; ++n) {
        float v = part[n];
        v += __shfl_xor(v, 16, 64);
        v += __shfl_xor(v, 32, 64);
        if (q == 0) out[(size_t)bi * 256 + w * 32 + n * 16 + r] = 512.f - 2.f * v;
    }
}

extern "C" void kernel_launch(void* const* d_in, const int* in_sizes, int n_in,
                              void* d_out, int out_size, void* d_ws, size_t ws_size,
                              hipStream_t stream) {
    (void)in_sizes; (void)n_in; (void)out_size; (void)ws_size;
    const float* inputs = (const float*)d_in[0];
    const float* adj    = (const float*)d_in[1];
    const float* W1     = (const float*)d_in[2];
    const float* g1     = (const float*)d_in[3];
    const float* b1     = (const float*)d_in[4];
    const float* m1     = (const float*)d_in[5];
    const float* v1     = (const float*)d_in[6];
    const float* W2     = (const float*)d_in[7];
    const float* g2     = (const float*)d_in[8];
    const float* b2     = (const float*)d_in[9];
    const float* m2     = (const float*)d_in[10];
    const float* v2     = (const float*)d_in[11];
    float* out = (float*)d_out;
    float* wsf = (float*)d_ws;

    prep_scalars<<<1, 256, 0, stream>>>(g1, b1, m1, v1, g2, b2, m2, v2, wsf);
    prep_w1f<<<4, 256, 0, stream>>>(W1, wsf);
    prep_w2f<<<32, 256, 0, stream>>>(W2, g2, v2, wsf);
    prep_p<<<1024, 256, 0, stream>>>(inputs, W1, wsf);
    propmain<<<1024, 512, 0, stream>>>(adj, wsf, out);
}